// Round 2
// baseline (17925.743 us; speedup 1.0000x reference)
//
#include <hip/hip_runtime.h>

// ---------------- im2col: x[B,3,224,224] -> patches[6272,768] fp32 ----------------
__global__ __launch_bounds__(256) void im2col_f32(const float* __restrict__ x,
                                                  float* __restrict__ patches) {
  int idx = blockIdx.x * 256 + threadIdx.x;
  if (idx >= 6272 * 192) return;
  int k4 = idx % 192, r = idx / 192;
  int k = k4 * 4;
  int c = k >> 8, py = (k >> 4) & 15, px = k & 15;
  int t = r % 196, b = r / 196;
  int gy = t / 14, gx = t % 14;
  float4 f = *(const float4*)(x + (((size_t)(b * 3 + c) * 224 + gy * 16 + py) * 224 + gx * 16 + px));
  *(float4*)(patches + (size_t)r * 768 + k) = f;
}

// ---------------- assemble h[6304,768] fp32 = [cls | pe+pos] ----------------
__global__ __launch_bounds__(256) void assemble_h(const float* __restrict__ pe,
                                                  const float* __restrict__ pos,
                                                  const float* __restrict__ cls,
                                                  float* __restrict__ h) {
  int idx = blockIdx.x * 256 + threadIdx.x;
  if (idx >= 6304 * 192) return;
  int d4 = idx % 192, row = idx / 192;
  int t = row % 197, b = row / 197;
  int d = d4 * 4;
  float4 v;
  if (t == 0) {
    v = *(const float4*)(cls + d);
  } else {
    v = *(const float4*)(pe + ((size_t)(b * 196 + (t - 1))) * 768 + d);
    float4 p = *(const float4*)(pos + (size_t)(t - 1) * 768 + d);
    v.x += p.x; v.y += p.y; v.z += p.z; v.w += p.w;
  }
  *(float4*)(h + (size_t)row * 768 + d) = v;
}

// ---------------- LayerNorm (row=768) fp32 -> fp32 ----------------
__global__ __launch_bounds__(256) void layernorm_f32(const float* __restrict__ x,
                                                     const float* __restrict__ w,
                                                     const float* __restrict__ b,
                                                     float* __restrict__ y, long long xstride) {
  long long row = blockIdx.x;
  const float* xr = x + row * xstride;
  int tid = threadIdx.x;
  float v0 = xr[tid], v1 = xr[tid + 256], v2 = xr[tid + 512];
  float s = v0 + v1 + v2;
  float ss = v0 * v0 + v1 * v1 + v2 * v2;
  for (int off = 32; off; off >>= 1) {
    s += __shfl_xor(s, off);
    ss += __shfl_xor(ss, off);
  }
  __shared__ float red[8];
  int wv = tid >> 6;
  if ((tid & 63) == 0) { red[wv] = s; red[wv + 4] = ss; }
  __syncthreads();
  s = red[0] + red[1] + red[2] + red[3];
  ss = red[4] + red[5] + red[6] + red[7];
  float mean = s * (1.0f / 768.0f);
  float var = ss * (1.0f / 768.0f) - mean * mean;
  float rstd = rsqrtf(var + 1e-5f);
  float* yr = y + row * 768;
  yr[tid] = (v0 - mean) * rstd * w[tid] + b[tid];
  yr[tid + 256] = (v1 - mean) * rstd * w[tid + 256] + b[tid + 256];
  yr[tid + 512] = (v2 - mean) * rstd * w[tid + 512] + b[tid + 512];
}

// ---------------- generic batched NT GEMM, pure fp32 (correctness anchor) ----------------
// C[m,n] = act(sum_k A[m,k]*W[n,k] + bias[n]) (+ Res[m,n])
// batch z: off = (z/Hdiv)*off1 + (z%Hdiv)*off2 per tensor (element offsets)
// flags: 1=gelu, 2=bias, 4=residual
__global__ __launch_bounds__(256) void gemm_f32(
    const float* A, const float* W, const float* bias, const float* Res, float* C,
    int M, int N, int K, int lda, int ldw, int ldc,
    long long offA1, long long offA2, long long offW1, long long offW2,
    long long offC1, long long offC2, int Hdiv, int flags) {
  int bz = blockIdx.z;
  int zh = bz / Hdiv, zl = bz - zh * Hdiv;
  A += (size_t)zh * offA1 + (size_t)zl * offA2;
  W += (size_t)zh * offW1 + (size_t)zl * offW2;
  long long coff = (long long)zh * offC1 + (long long)zl * offC2;

  __shared__ float As[16][68];  // [k][m], padded row so b128 reads stay 16B-aligned
  __shared__ float Ws[16][68];  // [k][n]
  int tid = threadIdx.x;
  int m0 = blockIdx.y * 64, n0 = blockIdx.x * 64;
  int tx = tid & 15, ty = tid >> 4;  // tx -> n dir, ty -> m dir
  float acc[4][4] = {};
  int r = tid >> 2, c4 = (tid & 3) * 4;  // stage 64 rows x 16 k, float4 per thread

  for (int k0 = 0; k0 < K; k0 += 16) {
    float4 av = {0.f, 0.f, 0.f, 0.f}, wv = {0.f, 0.f, 0.f, 0.f};
    if (m0 + r < M) av = *(const float4*)(A + (size_t)(m0 + r) * lda + k0 + c4);
    if (n0 + r < N) wv = *(const float4*)(W + (size_t)(n0 + r) * ldw + k0 + c4);
    __syncthreads();
    As[c4 + 0][r] = av.x; As[c4 + 1][r] = av.y; As[c4 + 2][r] = av.z; As[c4 + 3][r] = av.w;
    Ws[c4 + 0][r] = wv.x; Ws[c4 + 1][r] = wv.y; Ws[c4 + 2][r] = wv.z; Ws[c4 + 3][r] = wv.w;
    __syncthreads();
#pragma unroll
    for (int kk = 0; kk < 16; kk++) {
      float a[4], b[4];
#pragma unroll
      for (int i = 0; i < 4; i++) a[i] = As[kk][ty * 4 + i];
#pragma unroll
      for (int j = 0; j < 4; j++) b[j] = Ws[kk][tx * 4 + j];
#pragma unroll
      for (int i = 0; i < 4; i++)
#pragma unroll
        for (int j = 0; j < 4; j++) acc[i][j] += a[i] * b[j];
    }
  }

  bool gelu = flags & 1, hasb = flags & 2, hasr = flags & 4;
#pragma unroll
  for (int i = 0; i < 4; i++) {
    int m = m0 + ty * 4 + i;
    if (m >= M) continue;
#pragma unroll
    for (int j = 0; j < 4; j++) {
      int n = n0 + tx * 4 + j;
      if (n >= N) continue;
      float v = acc[i][j];
      if (hasb) v += bias[n];
      if (gelu) v = 0.5f * v * (1.0f + erff(v * 0.70710678118f));
      if (hasr) v += Res[coff + (size_t)m * ldc + n];
      C[coff + (size_t)m * ldc + n] = v;
    }
  }
}

// ---------------- softmax in-place on S[384*197,224] fp32 ----------------
__global__ __launch_bounds__(64) void softmax_f32(float* __restrict__ S) {
  size_t row = blockIdx.x;
  float* s = S + row * 224;
  int t = threadIdx.x;
  float v[4];
  float mx = -1e30f;
#pragma unroll
  for (int u = 0; u < 4; u++) {
    int j = t + u * 64;
    v[u] = (j < 197) ? s[j] * 8.0f : -1e30f;  // faithful bug: scores * sqrt(head_dim)
    mx = fmaxf(mx, v[u]);
  }
  for (int off = 32; off; off >>= 1) mx = fmaxf(mx, __shfl_xor(mx, off));
  float sum = 0.f;
#pragma unroll
  for (int u = 0; u < 4; u++) {
    int j = t + u * 64;
    v[u] = (j < 197) ? __expf(v[u] - mx) : 0.f;
    sum += v[u];
  }
  for (int off = 32; off; off >>= 1) sum += __shfl_xor(sum, off);
  float inv = 1.0f / sum;
#pragma unroll
  for (int u = 0; u < 4; u++) {
    int j = t + u * 64;
    if (j < 224) s[j] = v[u] * inv;  // cols 197..223 become exact 0 for the PV GEMM
  }
}

// ---------------- V transpose: qkv fp32 -> Vt[384][64][224] fp32 (zero-padded) ----------------
__global__ __launch_bounds__(256) void v_transpose_f32(const float* __restrict__ qkv,
                                                       float* __restrict__ Vt) {
  int bh = blockIdx.y;
  int b = bh / 12, h = bh % 12;
  int j0 = blockIdx.x * 64;
  __shared__ float tbuf[64][65];
  int tid = threadIdx.x;
  int d = tid & 63;
  for (int jj = tid >> 6; jj < 64; jj += 4) {
    int j = j0 + jj;
    float val = 0.f;
    if (j < 197) val = qkv[(size_t)(b * 197 + j) * 2304 + 1536 + h * 64 + d];
    tbuf[jj][d] = val;
  }
  __syncthreads();
  int jl = tid & 63;
  int jc = j0 + jl;
  for (int dd = tid >> 6; dd < 64; dd += 4) {
    if (jc < 224) Vt[((size_t)bh * 64 + dd) * 224 + jc] = tbuf[jl][dd];
  }
}

// ---------------- head: out[32,1000] = cls_ln @ head_w^T + head_b (exact fp32) ----------------
__global__ __launch_bounds__(256) void head_kernel(const float* __restrict__ cls,
                                                   const float* __restrict__ hw,
                                                   const float* __restrict__ hb,
                                                   float* __restrict__ out) {
  int b = blockIdx.x;
  __shared__ float xr[768];
  for (int d = threadIdx.x; d < 768; d += 256) xr[d] = cls[(size_t)b * 768 + d];
  __syncthreads();
  for (int n = threadIdx.x; n < 1000; n += 256) {
    const float* wr = hw + (size_t)n * 768;
    float acc = 0.f;
    for (int d = 0; d < 768; d += 4) {
      float4 xx = *(const float4*)(xr + d);
      float4 ww = *(const float4*)(wr + d);
      acc += xx.x * ww.x + xx.y * ww.y + xx.z * ww.z + xx.w * ww.w;
    }
    out[(size_t)b * 1000 + n] = acc + hb[n];
  }
}

extern "C" void kernel_launch(void* const* d_in, const int* in_sizes, int n_in,
                              void* d_out, int out_size, void* d_ws, size_t ws_size,
                              hipStream_t stream) {
  const float* x       = (const float*)d_in[0];
  const float* patch_w = (const float*)d_in[1];
  const float* patch_b = (const float*)d_in[2];
  const float* pos     = (const float*)d_in[3];
  const float* cls     = (const float*)d_in[4];
  const float* ln1_w   = (const float*)d_in[5];
  const float* ln1_b   = (const float*)d_in[6];
  const float* qkv_w   = (const float*)d_in[7];
  const float* qkv_b   = (const float*)d_in[8];
  const float* proj_w  = (const float*)d_in[9];
  const float* proj_b  = (const float*)d_in[10];
  const float* ln2_w   = (const float*)d_in[11];
  const float* ln2_b   = (const float*)d_in[12];
  const float* fc1_w   = (const float*)d_in[13];
  const float* fc1_b   = (const float*)d_in[14];
  const float* fc2_w   = (const float*)d_in[15];
  const float* fc2_b   = (const float*)d_in[16];
  const float* ln_w    = (const float*)d_in[17];
  const float* ln_b    = (const float*)d_in[18];
  const float* head_w  = (const float*)d_in[19];
  const float* head_b  = (const float*)d_in[20];
  float* out = (float*)d_out;

  char* base = (char*)d_ws;
  size_t off = 0;
  auto alloc = [&](size_t bytes) {
    void* p = base + off;
    off = (off + bytes + 255) & ~(size_t)255;
    return p;
  };

  // total ~216 MB
  float* h      = (float*)alloc(6304ull * 768 * 4);
  float* y      = (float*)alloc(6304ull * 768 * 4);
  float* qkvb   = (float*)alloc(6304ull * 2304 * 4);
  float* Vt     = (float*)alloc(384ull * 64 * 224 * 4);
  float* o      = (float*)alloc(6304ull * 768 * 4);
  float* cls_ln = (float*)alloc(32ull * 768 * 4);
  // overlapped region: prologue {patches, pe} / attention {Sb} / MLP {mb}
  char* R = (char*)alloc(6304ull * 3072 * 4);  // 77.5 MB = max phase need
  float* patches = (float*)R;
  float* pe      = (float*)(R + 6272ull * 768 * 4);
  float* Sb      = (float*)R;  // [384][197][224]
  float* mb      = (float*)R;  // [6304][3072]

  // ---- patch embed ----
  im2col_f32<<<4704, 256, 0, stream>>>(x, patches);
  gemm_f32<<<dim3(12, 98, 1), 256, 0, stream>>>(
      patches, patch_w, patch_b, nullptr, pe,
      6272, 768, 768, 768, 768, 768, 0, 0, 0, 0, 0, 0, 1, 2);
  assemble_h<<<4728, 256, 0, stream>>>(pe, pos, cls, h);

  // ---- transformer layers ----
  for (int l = 0; l < 12; ++l) {
    layernorm_f32<<<6304, 256, 0, stream>>>(h, ln1_w + l * 768, ln1_b + l * 768, y, 768);
    gemm_f32<<<dim3(36, 99, 1), 256, 0, stream>>>(
        y, qkv_w + (size_t)l * 1769472, qkv_b + l * 2304, nullptr, qkvb,
        6304, 2304, 768, 768, 768, 2304, 0, 0, 0, 0, 0, 0, 1, 2);
    v_transpose_f32<<<dim3(4, 384), 256, 0, stream>>>(qkvb, Vt);
    // scores: per (b,h): Q[197,64] @ K[197,64]^T -> Sb
    gemm_f32<<<dim3(4, 4, 384), 256, 0, stream>>>(
        qkvb, qkvb + 768, nullptr, nullptr, Sb,
        197, 197, 64, 2304, 2304, 224,
        197LL * 2304, 64LL, 197LL * 2304, 64LL, 12LL * 44128, 44128LL, 12, 0);
    softmax_f32<<<75648, 64, 0, stream>>>(Sb);
    // P @ V: per (b,h): [197,224] @ Vt[64,224]^T -> o[b,t,h*64+d]
    gemm_f32<<<dim3(1, 4, 384), 256, 0, stream>>>(
        Sb, Vt, nullptr, nullptr, o,
        197, 64, 224, 224, 224, 768,
        12LL * 44128, 44128LL, 12LL * 14336, 14336LL, 197LL * 768, 64LL, 12, 0);
    gemm_f32<<<dim3(12, 99, 1), 256, 0, stream>>>(
        o, proj_w + (size_t)l * 589824, proj_b + l * 768, h, h,
        6304, 768, 768, 768, 768, 768, 0, 0, 0, 0, 0, 0, 1, 2 | 4);
    layernorm_f32<<<6304, 256, 0, stream>>>(h, ln2_w + l * 768, ln2_b + l * 768, y, 768);
    gemm_f32<<<dim3(48, 99, 1), 256, 0, stream>>>(
        y, fc1_w + (size_t)l * 2359296, fc1_b + l * 3072, nullptr, mb,
        6304, 3072, 768, 768, 768, 3072, 0, 0, 0, 0, 0, 0, 1, 2 | 1);
    gemm_f32<<<dim3(12, 99, 1), 256, 0, stream>>>(
        mb, fc2_w + (size_t)l * 2359296, fc2_b + l * 768, h, h,
        6304, 768, 3072, 3072, 3072, 768, 0, 0, 0, 0, 0, 0, 1, 2 | 4);
  }

  // ---- final LN (cls rows only) + head ----
  layernorm_f32<<<32, 256, 0, stream>>>(h, ln_w, ln_b, cls_ln, 197LL * 768);
  head_kernel<<<32, 256, 0, stream>>>(cls_ln, head_w, head_b, out);
}